// Round 12
// baseline (814.255 us; speedup 1.0000x reference)
//
#include <hip/hip_runtime.h>
#include <hip/hip_bf16.h>
#include <stddef.h>

// Problem constants
constexpr int E_ = 8;
constexpr int C_ = 1024;
constexpr int M_ = 2048;
constexpr int H_ = 8192;
constexpr int O_ = 2048;

typedef __bf16 bf16;
typedef __bf16 bf16x4 __attribute__((ext_vector_type(4)));
typedef __bf16 bf16x8 __attribute__((ext_vector_type(8)));
typedef float  f32x4  __attribute__((ext_vector_type(4)));

#define GLOAD16(src, dst)                                                        \
    __builtin_amdgcn_global_load_lds(                                            \
        (const __attribute__((address_space(1))) void*)(src),                    \
        (__attribute__((address_space(3))) void*)(dst), 16, 0, 0)

#define BARRIER()  __builtin_amdgcn_s_barrier()
#define LGKM0()    do { asm volatile("s_waitcnt lgkmcnt(0)" ::: "memory");       \
                        __builtin_amdgcn_sched_barrier(0); } while (0)
#define VMCNT(n)   asm volatile("s_waitcnt vmcnt(" #n ")" ::: "memory")

// ---------------------------------------------------------------------------
// fp32 -> bf16 convert (grid-stride, 32B-read/16B-write per lane)
// ---------------------------------------------------------------------------
__global__ __launch_bounds__(256)
void cvt_f32_bf16(const float* __restrict__ in, bf16* __restrict__ out, size_t n)
{
    size_t i = ((size_t)blockIdx.x * blockDim.x + threadIdx.x) * 8;
    const size_t stride = (size_t)gridDim.x * blockDim.x * 8;
    for (; i < n; i += stride) {
        f32x4 v0 = *(const f32x4*)(in + i);
        f32x4 v1 = *(const f32x4*)(in + i + 4);
        bf16x8 o;
#pragma unroll
        for (int j = 0; j < 4; ++j) { o[j] = (bf16)v0[j]; o[j + 4] = (bf16)v1[j]; }
        *(bf16x8*)(out + i) = o;
    }
}

// ---------------------------------------------------------------------------
// Transpose+convert: W2 [E, H, O] fp32 -> W2t [gridDim.z, O, H] bf16
// ---------------------------------------------------------------------------
__global__ __launch_bounds__(256)
void transpose_w2(const float* __restrict__ W2, bf16* __restrict__ W2t, int e0)
{
    const int e  = e0 + blockIdx.z;
    const int oo = blockIdx.x;  // O/64
    const int ho = blockIdx.y;  // H/64
    const int tid = threadIdx.x;

    __shared__ bf16 t[64][72];  // 144B rows: 16B-aligned bf16x8 reads

    const float* src = W2 + (size_t)e * H_ * O_ + (size_t)(ho * 64) * O_ + oo * 64;
#pragma unroll
    for (int p = 0; p < 4; ++p) {
        const int h  = p * 16 + (tid >> 4);
        const int o4 = (tid & 15) * 4;
        f32x4 v = *(const f32x4*)(src + (size_t)h * O_ + o4);
#pragma unroll
        for (int q = 0; q < 4; ++q) t[o4 + q][h] = (bf16)v[q];
    }
    __syncthreads();

    bf16* dst = W2t + (size_t)blockIdx.z * O_ * H_ + (size_t)(oo * 64) * H_ + ho * 64;
#pragma unroll
    for (int p2 = 0; p2 < 2; ++p2) {
        const int o  = p2 * 32 + (tid >> 3);
        const int h8 = (tid & 7) * 8;
        bf16x8 v = *(const bf16x8*)(&t[o][h8]);
        *(bf16x8*)(dst + (size_t)o * H_ + h8) = v;
    }
}

// ---------------------------------------------------------------------------
// 256x256-tile 8-phase grouped GEMM, BK=64, 2 K-tiles/iter, 512 thr = 8 waves
// (2M x 4N), wave tile 128x64, acc[8][4] f32x4.
// LDS 128 KiB: dbuf (K-tile g -> g&1), each 64 KiB = A0@0 A1@16K B0@32K B1@48K.
// Swizzle: 16B chunk c of row r stored at c^(r&7) (pre-swizzled gload source /
// ds_write addr + swizzled ds_read addr) -> conflict-free b128 reads.
//
// BF32=false (gemm2, r3-proven, UNCHANGED): B staged bf16 via global_load_lds
//   ph2/3 (gb), ph6/7 (gc); A staged ph0/1, ph4/5; counted VMCNT(4)@ph3/ph7.
// BF32=true (gemm1, r12 EARLY-A-STAGE variant): B from fp32 global, 3-phase
//   load lead (ph0->cvt ph3, ph4->cvt ph7; blb/blc iteration-local, 32 regs).
//   A-stages moved to the earliest hazard-legal slots: stageA(gb)@ph3 (dbuf0-A
//   read-drained at ph2's closing barrier) and stageA(gc)@ph7 (dbuf1-A drained
//   at ph6) -> 4-phase leads. Each cvtwriteB's compiler-auto vmcnt (3-phase-old
//   f32 loads) retires every older A-stage in the in-order queue, so explicit
//   waits become counted VMCNT(4) (only the just-issued A-stages outstanding).
//   Last iter: VMCNT(0)@ph3 retires the 4-phase-old A(ga). Region hazards:
//   B dbuf last read ph1/ph5 (LGKM0+barrier), cvt-written ph3/ph7; A regions
//   re-staged >=1 barrier after their last reader's closing barrier; writes
//   drain at own-phase LGKM0; first cross-wave read is >=1 barrier later.
// ---------------------------------------------------------------------------
template<int KDIM, bool RELU_BF16, bool BF32>
__global__ __launch_bounds__(512, 2)
void gemm256(const bf16* __restrict__ A, const void* __restrict__ Bv,
             const float* __restrict__ bias, void* __restrict__ OutP,
             int nBM, int nBN)
{
    extern __shared__ char smem[];                  // 131072 B
    constexpr int K2  = KDIM * 2;                   // bf16 row stride bytes
    constexpr int NIT = KDIM / 128;                 // iterations (2 K-tiles each)

    const int tid  = threadIdx.x;
    const int lane = tid & 63;
    const int wid  = tid >> 6;
    const int wr = wid >> 2, wc = wid & 3;
    const int fr = lane & 15, fq = lane >> 4;

    // XCD-aware bijective block swizzle (grid % 8 == 0 by construction)
    const int nwg = gridDim.x;
    const int cpx = nwg >> 3;
    const int b0  = blockIdx.x;
    const int wg  = (b0 & 7) * cpx + (b0 >> 3);
    const int per_e = nBM * nBN;
    const int e  = wg / per_e;
    const int rr = wg - e * per_e;
    const int bn = rr / nBM;
    const int bm = rr - bn * nBM;      // bm fastest: 4 wgs sharing a B panel are
                                       // consecutive -> same XCD after swizzle
    const int MROWS = nBM * 256;
    const int NROWS = nBN * 256;

    const char*  Apan   = (const char*)(A + (size_t)e * MROWS * KDIM + (size_t)bm * 256 * KDIM);
    const char*  Bpan   = (const char*)((const bf16*)Bv + (size_t)e * NROWS * KDIM + (size_t)bn * 256 * KDIM);
    const float* Bpan32 = (const float*)Bv + (size_t)e * NROWS * KDIM + (size_t)bn * 256 * KDIM;

    const int r0  = tid >> 3;                       // 0..63
    const int wsw = ((tid & 7) << 4) ^ ((r0 & 7) << 4);

    auto stageA = [&](int gk, int comp) {           // comp: 0/1 = A row-half
        char* lds = smem + (gk & 1) * 65536 + comp * 16384 + tid * 16;
        const char* src = Apan + (size_t)((comp << 7) + r0) * K2 + (size_t)gk * 128 + wsw;
        GLOAD16(src, lds);
        GLOAD16(src + (size_t)64 * K2, lds + 8192);
    };
    auto stageB16 = [&](int gk, int comp2) {        // bf16 path
        char* lds = smem + (gk & 1) * 65536 + 32768 + comp2 * 16384 + tid * 16;
        const char* src = Bpan + (size_t)((comp2 << 7) + r0) * K2 + (size_t)gk * 128 + wsw;
        GLOAD16(src, lds);
        GLOAD16(src + (size_t)64 * K2, lds + 8192);
    };
    // fp32 path: load BOTH B halves of K-tile g (rows r0, r0+64, 128+r0, 192+r0)
    auto loadB32 = [&](int g, f32x4* d) {
        const float* s0 = Bpan32 + (size_t)r0 * KDIM + g * 64 + (tid & 7) * 8;
        d[0] = *(const f32x4*)s0;
        d[1] = *(const f32x4*)(s0 + 4);
        d[2] = *(const f32x4*)(s0 + (size_t)64 * KDIM);
        d[3] = *(const f32x4*)(s0 + (size_t)64 * KDIM + 4);
        const float* s1 = s0 + (size_t)128 * KDIM;
        d[4] = *(const f32x4*)s1;
        d[5] = *(const f32x4*)(s1 + 4);
        d[6] = *(const f32x4*)(s1 + (size_t)64 * KDIM);
        d[7] = *(const f32x4*)(s1 + (size_t)64 * KDIM + 4);
    };
    auto cvtwriteB = [&](int g, const f32x4* d) {
        bf16x8 h0, h1, h2, h3;
#pragma unroll
        for (int j = 0; j < 4; ++j) {
            h0[j] = (bf16)d[0][j]; h0[4 + j] = (bf16)d[1][j];
            h1[j] = (bf16)d[2][j]; h1[4 + j] = (bf16)d[3][j];
            h2[j] = (bf16)d[4][j]; h2[4 + j] = (bf16)d[5][j];
            h3[j] = (bf16)d[6][j]; h3[4 + j] = (bf16)d[7][j];
        }
        char* dst = smem + (g & 1) * 65536 + 32768 + r0 * 128 + wsw;
        *(bf16x8*)dst = h0;
        *(bf16x8*)(dst + 8192)  = h1;
        *(bf16x8*)(dst + 16384) = h2;
        *(bf16x8*)(dst + 24576) = h3;
    };

    // fragment-read lane constants: chunk c = kk*4+fq, swizzled c^(fr&7)
    const int frq = fr & 7;
    const int cA0 = ((fq    ) ^ frq) << 4;
    const int cA1 = ((4 | fq) ^ frq) << 4;
    const int aoff = wr * 16384 + fr * 128;
    const int boff = 32768 + (wc >> 1) * 16384 + (wc & 1) * 8192 + fr * 128;

    bf16x8 av[4][2];
    bf16x8 bv[4][2];
    f32x4 acc[8][4];
#pragma unroll
    for (int m = 0; m < 8; ++m)
#pragma unroll
        for (int n = 0; n < 4; ++n) acc[m][n] = (f32x4){0.f, 0.f, 0.f, 0.f};

    auto loadA = [&](const char* base, int mh) {
#pragma unroll
        for (int mm = 0; mm < 4; ++mm) {
            const char* p = base + aoff + (mh * 4 + mm) * 2048;
            av[mm][0] = *(const bf16x8*)(p + cA0);
            av[mm][1] = *(const bf16x8*)(p + cA1);
        }
    };
    auto loadB = [&](const char* base, int nh) {
#pragma unroll
        for (int nn = 0; nn < 2; ++nn) {
            const char* p = base + boff + (nh * 2 + nn) * 2048;
            bv[nh * 2 + nn][0] = *(const bf16x8*)(p + cA0);
            bv[nh * 2 + nn][1] = *(const bf16x8*)(p + cA1);
        }
    };
    auto mmaq = [&](int mh, int nh) {
        __builtin_amdgcn_s_setprio(1);
#pragma unroll
        for (int mm = 0; mm < 4; ++mm)
#pragma unroll
            for (int nn = 0; nn < 2; ++nn) {
                const int m = mh * 4 + mm, n = nh * 2 + nn;
                acc[m][n] = __builtin_amdgcn_mfma_f32_16x16x32_bf16(av[mm][0], bv[n][0], acc[m][n], 0, 0, 0);
                acc[m][n] = __builtin_amdgcn_mfma_f32_16x16x32_bf16(av[mm][1], bv[n][1], acc[m][n], 0, 0, 0);
            }
        __builtin_amdgcn_s_setprio(0);
    };

    // ---- prologue: K-tiles 0,1 fully resident ----
    if constexpr (BF32) {
        f32x4 p0[8], p1[8];
        loadB32(0, p0); loadB32(1, p1);             // oldest in queue
        stageA(0, 0); stageA(0, 1);
        stageA(1, 0); stageA(1, 1);                 // A(1) now from prologue
        cvtwriteB(0, p0);                           // auto-wait: vmcnt(16)
        cvtwriteB(1, p1);                           // auto-wait: vmcnt(8)
        VMCNT(0);                                   // A(0),A(1) resident
        asm volatile("s_waitcnt lgkmcnt(0)" ::: "memory");
        BARRIER();
    } else {
        stageB16(0, 0); stageB16(0, 1); stageA(0, 0); stageA(0, 1);
        stageB16(1, 0); stageB16(1, 1);
        VMCNT(4);
        BARRIER();
    }

    for (int t = 0; t < NIT; ++t) {
        const bool nl = (t + 1 < NIT);
        const char* d0b = smem;             // K-tile 2t   (dbuf0)
        const char* d1b = smem + 65536;     // K-tile 2t+1 (dbuf1)
        const int ga = 2 * t + 1;
        const int gb = 2 * t + 2;
        const int gc = 2 * t + 3;
        f32x4 blb[8], blc[8];

        // ---- K-tile a (dbuf0) ----
        loadB(d0b, 0); loadA(d0b, 0);       // ph0
        if constexpr (BF32) { if (nl) loadB32(gb, blb); }
        else                { stageA(ga, 0); }
        BARRIER(); LGKM0();
        mmaq(0, 0);
        BARRIER();

        loadB(d0b, 1);                      // ph1
        if constexpr (!BF32) { stageA(ga, 1); }
        BARRIER(); LGKM0();
        mmaq(0, 1);
        BARRIER();

        loadA(d0b, 1);                      // ph2
        if constexpr (!BF32) { if (nl) stageB16(gb, 0); }
        BARRIER(); LGKM0();
        mmaq(1, 1);
        BARRIER();

        // ph3: BF32 stages next dbuf0-A here (read-drained at ph2's barrier);
        // cvt's auto-wait (3-ph-old f32 loads) retires the prev-ph7 A(ga).
        if constexpr (BF32) { if (nl) { cvtwriteB(gb, blb); stageA(gb, 0); stageA(gb, 1); } }
        else                { if (nl) stageB16(gb, 1); }
        BARRIER(); LGKM0();
        mmaq(1, 0);
        if (nl) { VMCNT(4); } else { VMCNT(0); }
        BARRIER();

        // ---- K-tile b (dbuf1) ----
        loadB(d1b, 0); loadA(d1b, 0);       // ph4
        if constexpr (BF32) { if (nl) loadB32(gc, blc); }
        else                { if (nl) stageA(gb, 0); }
        BARRIER(); LGKM0();
        mmaq(0, 0);
        BARRIER();

        loadB(d1b, 1);                      // ph5
        if constexpr (!BF32) { if (nl) stageA(gb, 1); }
        BARRIER(); LGKM0();
        mmaq(0, 1);
        BARRIER();

        loadA(d1b, 1);                      // ph6
        if constexpr (!BF32) { if (nl) stageB16(gc, 0); }
        BARRIER(); LGKM0();
        mmaq(1, 1);
        BARRIER();

        // ph7: BF32 stages next dbuf1-A (read-drained at ph6's barrier);
        // cvt(gc)'s auto-wait retires stageA(gb)@ph3 -> A(gb) resident.
        if constexpr (BF32) { if (nl) { cvtwriteB(gc, blc); stageA(gc, 0); stageA(gc, 1); } }
        else                { if (nl) stageB16(gc, 1); }
        BARRIER(); LGKM0();
        mmaq(1, 0);
        if (nl) {
            VMCNT(4);
            BARRIER();
        }
    }

    // epilogue
    const int gr0 = bm * 256 + wr * 128;
    const int gc0 = bn * 256 + wc * 64;
    if constexpr (RELU_BF16) {
        bf16* Out = (bf16*)OutP;
#pragma unroll
        for (int n = 0; n < 4; ++n) {
            const int col = gc0 + n * 16 + fr;
            const float bb = bias[(size_t)e * NROWS + col];
#pragma unroll
            for (int m = 0; m < 8; ++m)
#pragma unroll
                for (int j = 0; j < 4; ++j) {
                    float v = acc[m][n][j] + bb;
                    v = v > 0.f ? v : 0.f;
                    const int row = gr0 + m * 16 + fq * 4 + j;
                    Out[((size_t)e * MROWS + row) * NROWS + col] = (bf16)v;
                }
        }
    } else {
        float* Out = (float*)OutP;
#pragma unroll
        for (int n = 0; n < 4; ++n) {
            const int col = gc0 + n * 16 + fr;
            const float bb = bias[(size_t)e * NROWS + col];
#pragma unroll
            for (int m = 0; m < 8; ++m)
#pragma unroll
                for (int j = 0; j < 4; ++j) {
                    const int row = gr0 + m * 16 + fq * 4 + j;
                    Out[((size_t)e * MROWS + row) * NROWS + col] = acc[m][n][j] + bb;
                }
        }
    }
}

// ---------------------------------------------------------------------------
extern "C" void kernel_launch(void* const* d_in, const int* in_sizes, int n_in,
                              void* d_out, int out_size, void* d_ws, size_t ws_size,
                              hipStream_t stream)
{
    const float* x  = (const float*)d_in[0];
    const float* w1 = (const float*)d_in[1];
    const float* b1 = (const float*)d_in[2];
    const float* w2 = (const float*)d_in[3];
    const float* b2 = (const float*)d_in[4];
    float* out = (float*)d_out;

    (void)hipFuncSetAttribute(reinterpret_cast<const void*>(&gemm256<M_, true, true>),
                              hipFuncAttributeMaxDynamicSharedMemorySize, 131072);
    (void)hipFuncSetAttribute(reinterpret_cast<const void*>(&gemm256<H_, false, false>),
                              hipFuncAttributeMaxDynamicSharedMemorySize, 131072);

    const size_t xb_sz  = (size_t)E_ * C_ * M_ * sizeof(bf16);   //  32 MB
    const size_t w2t_sz = (size_t)E_ * O_ * H_ * sizeof(bf16);   // 256 MB
    const size_t y1_sz  = (size_t)E_ * C_ * H_ * sizeof(bf16);   // 128 MB

    if (ws_size >= xb_sz + w2t_sz + y1_sz) {
        bf16* xb  = (bf16*)d_ws;
        bf16* w2t = (bf16*)((char*)d_ws + xb_sz);
        bf16* y1  = (bf16*)((char*)d_ws + xb_sz + w2t_sz);

        cvt_f32_bf16<<<2048, 256, 0, stream>>>(x, xb, (size_t)E_ * C_ * M_);
        transpose_w2<<<dim3(O_ / 64, H_ / 64, E_), 256, 0, stream>>>(w2, w2t, 0);

        // gemm1: [E,1024,2048]bf16 x [E,8192,2048]fp32^T -> bf16 y1 (+bias,relu)
        gemm256<M_, true, true><<<dim3(8 * 4 * (H_ / 256)), 512, 131072, stream>>>(
            xb, w1, b1, y1, 4, H_ / 256);
        // gemm2: [E,1024,8192]bf16 x [E,2048,8192]bf16^T -> fp32 out (+bias)
        gemm256<H_, false, false><<<dim3(8 * 4 * (O_ / 256)), 512, 131072, stream>>>(
            y1, w2t, b2, out, 4, O_ / 256);
    } else {
        // per-expert fallback: 4 + 32 + 16 = 52 MB of ws
        bf16* xb  = (bf16*)d_ws;
        bf16* w2t = (bf16*)((char*)d_ws + (size_t)C_ * M_ * sizeof(bf16));
        bf16* y1  = (bf16*)((char*)d_ws + (size_t)C_ * M_ * sizeof(bf16)
                                        + (size_t)O_ * H_ * sizeof(bf16));
        for (int e = 0; e < E_; ++e) {
            cvt_f32_bf16<<<512, 256, 0, stream>>>(x + (size_t)e * C_ * M_, xb, (size_t)C_ * M_);
            transpose_w2<<<dim3(O_ / 64, H_ / 64, 1), 256, 0, stream>>>(w2, w2t, e);
            gemm256<M_, true, true><<<dim3(4 * (H_ / 256)), 512, 131072, stream>>>(
                xb, w1 + (size_t)e * H_ * M_, b1 + (size_t)e * H_, y1, 4, H_ / 256);
            gemm256<H_, false, false><<<dim3(4 * (O_ / 256)), 512, 131072, stream>>>(
                y1, w2t, b2 + (size_t)e * O_, out + (size_t)e * C_ * O_, 4, O_ / 256);
        }
    }
}

// Round 13
// 780.328 us; speedup vs baseline: 1.0435x; 1.0435x over previous
//
#include <hip/hip_runtime.h>
#include <hip/hip_bf16.h>
#include <stddef.h>

// Problem constants
constexpr int E_ = 8;
constexpr int C_ = 1024;
constexpr int M_ = 2048;
constexpr int H_ = 8192;
constexpr int O_ = 2048;

typedef __bf16 bf16;
typedef __bf16 bf16x4 __attribute__((ext_vector_type(4)));
typedef __bf16 bf16x8 __attribute__((ext_vector_type(8)));
typedef float  f32x4  __attribute__((ext_vector_type(4)));

#define GLOAD16(src, dst)                                                        \
    __builtin_amdgcn_global_load_lds(                                            \
        (const __attribute__((address_space(1))) void*)(src),                    \
        (__attribute__((address_space(3))) void*)(dst), 16, 0, 0)

#define BARRIER()  __builtin_amdgcn_s_barrier()
#define LGKM0()    do { asm volatile("s_waitcnt lgkmcnt(0)" ::: "memory");       \
                        __builtin_amdgcn_sched_barrier(0); } while (0)
#define VMCNT(n)   asm volatile("s_waitcnt vmcnt(" #n ")" ::: "memory")

// ---------------------------------------------------------------------------
// fp32 -> bf16 convert (grid-stride, 32B-read/16B-write per lane)
// ---------------------------------------------------------------------------
__global__ __launch_bounds__(256)
void cvt_f32_bf16(const float* __restrict__ in, bf16* __restrict__ out, size_t n)
{
    size_t i = ((size_t)blockIdx.x * blockDim.x + threadIdx.x) * 8;
    const size_t stride = (size_t)gridDim.x * blockDim.x * 8;
    for (; i < n; i += stride) {
        f32x4 v0 = *(const f32x4*)(in + i);
        f32x4 v1 = *(const f32x4*)(in + i + 4);
        bf16x8 o;
#pragma unroll
        for (int j = 0; j < 4; ++j) { o[j] = (bf16)v0[j]; o[j + 4] = (bf16)v1[j]; }
        *(bf16x8*)(out + i) = o;
    }
}

// ---------------------------------------------------------------------------
// Transpose+convert: W2 [E, H, O] fp32 -> W2t [gridDim.z, O, H] bf16
// ---------------------------------------------------------------------------
__global__ __launch_bounds__(256)
void transpose_w2(const float* __restrict__ W2, bf16* __restrict__ W2t, int e0)
{
    const int e  = e0 + blockIdx.z;
    const int oo = blockIdx.x;  // O/64
    const int ho = blockIdx.y;  // H/64
    const int tid = threadIdx.x;

    __shared__ bf16 t[64][72];  // 144B rows: 16B-aligned bf16x8 reads

    const float* src = W2 + (size_t)e * H_ * O_ + (size_t)(ho * 64) * O_ + oo * 64;
#pragma unroll
    for (int p = 0; p < 4; ++p) {
        const int h  = p * 16 + (tid >> 4);
        const int o4 = (tid & 15) * 4;
        f32x4 v = *(const f32x4*)(src + (size_t)h * O_ + o4);
#pragma unroll
        for (int q = 0; q < 4; ++q) t[o4 + q][h] = (bf16)v[q];
    }
    __syncthreads();

    bf16* dst = W2t + (size_t)blockIdx.z * O_ * H_ + (size_t)(oo * 64) * H_ + ho * 64;
#pragma unroll
    for (int p2 = 0; p2 < 2; ++p2) {
        const int o  = p2 * 32 + (tid >> 3);
        const int h8 = (tid & 7) * 8;
        bf16x8 v = *(const bf16x8*)(&t[o][h8]);
        *(bf16x8*)(dst + (size_t)o * H_ + h8) = v;
    }
}

// ---------------------------------------------------------------------------
// 256x256-tile 8-phase grouped GEMM, BK=64, 2 K-tiles/iter, 512 thr = 8 waves
// (2M x 4N), wave tile 128x64, acc[8][4] f32x4.
// LDS 128 KiB: dbuf (K-tile g -> g&1), each 64 KiB = A0@0 A1@16K B0@32K B1@48K
// (half = 128 rows x 64 k x 2B, rows of 128B). Swizzle: 16B chunk c of row r
// stored at c^(r&7); applied on pre-swizzled gload source / ds_write addr,
// and on the ds_read fragment addr -> conflict-free b128 reads.
//
// BF32=false (gemm2): B staged bf16 via global_load_lds at ph2/3 (gb) and
//   ph6/7 (gc); counted VMCNT(4) at ph3/ph7 (r3-proven schedule).
// BF32=true (gemm1): B read from fp32 global with a 3-PHASE LEAD —
//   8 x f32x4 buffer-loads issued at ph0 (gb) / ph4 (gc); cvt+4 ds_write_b128
//   at ph3 / ph7. The cvt's compiler-auto vmcnt waits on loads ~3 phases old
//   and, by in-order queue position (B issued before the same-phase A
//   gload_lds), never force-retires younger A prefetches. VMCNT(0)@ph3/ph7
//   then waits only 2-3-phase-old stageA. Region hazards: dbuf B last read
//   ph1/ph5 (LGKM0 + barrier), written ph3/ph7 (>=2 barriers later); writes
//   drain at own-phase LGKM0 before the closing barrier; first cross-wave
//   read is next iter ph0.
//
// Session map (final): champion structure, reproduced at 782-783 µs twice
// (r6, r11). Measured dead ends: 2-blocks/CU (r7: launch_bounds 2nd arg is
// blocks/CU -> 64-VGPR spill), 16-wave (r8: spill), persistent bm (r5:
// epilogue stores serialize the vmcnt queue), deeper load leads (r10: +64
// persistent VGPR -> spill; r12: ph3/ph7 slot congestion), TN reg-transpose
// (r9: 32-way ds_write bank conflict), transpose bank fix (r10: neutral).
// ---------------------------------------------------------------------------
template<int KDIM, bool RELU_BF16, bool BF32>
__global__ __launch_bounds__(512, 2)
void gemm256(const bf16* __restrict__ A, const void* __restrict__ Bv,
             const float* __restrict__ bias, void* __restrict__ OutP,
             int nBM, int nBN)
{
    extern __shared__ char smem[];                  // 131072 B
    constexpr int K2  = KDIM * 2;                   // bf16 row stride bytes
    constexpr int NIT = KDIM / 128;                 // iterations (2 K-tiles each)

    const int tid  = threadIdx.x;
    const int lane = tid & 63;
    const int wid  = tid >> 6;
    const int wr = wid >> 2, wc = wid & 3;
    const int fr = lane & 15, fq = lane >> 4;

    // XCD-aware bijective block swizzle (grid % 8 == 0 by construction)
    const int nwg = gridDim.x;
    const int cpx = nwg >> 3;
    const int b0  = blockIdx.x;
    const int wg  = (b0 & 7) * cpx + (b0 >> 3);
    const int per_e = nBM * nBN;
    const int e  = wg / per_e;
    const int rr = wg - e * per_e;
    const int bn = rr / nBM;
    const int bm = rr - bn * nBM;      // bm fastest: 4 wgs sharing a B panel are
                                       // consecutive -> same XCD after swizzle
    const int MROWS = nBM * 256;
    const int NROWS = nBN * 256;

    const char*  Apan   = (const char*)(A + (size_t)e * MROWS * KDIM + (size_t)bm * 256 * KDIM);
    const char*  Bpan   = (const char*)((const bf16*)Bv + (size_t)e * NROWS * KDIM + (size_t)bn * 256 * KDIM);
    const float* Bpan32 = (const float*)Bv + (size_t)e * NROWS * KDIM + (size_t)bn * 256 * KDIM;

    const int r0  = tid >> 3;                       // 0..63
    const int wsw = ((tid & 7) << 4) ^ ((r0 & 7) << 4);

    auto stageA = [&](int gk, int comp) {           // comp: 0/1 = A row-half
        char* lds = smem + (gk & 1) * 65536 + comp * 16384 + tid * 16;
        const char* src = Apan + (size_t)((comp << 7) + r0) * K2 + (size_t)gk * 128 + wsw;
        GLOAD16(src, lds);
        GLOAD16(src + (size_t)64 * K2, lds + 8192);
    };
    auto stageB16 = [&](int gk, int comp2) {        // bf16 path
        char* lds = smem + (gk & 1) * 65536 + 32768 + comp2 * 16384 + tid * 16;
        const char* src = Bpan + (size_t)((comp2 << 7) + r0) * K2 + (size_t)gk * 128 + wsw;
        GLOAD16(src, lds);
        GLOAD16(src + (size_t)64 * K2, lds + 8192);
    };
    // fp32 path: load BOTH B halves of K-tile g (rows r0, r0+64, 128+r0, 192+r0)
    auto loadB32 = [&](int g, f32x4* d) {
        const float* s0 = Bpan32 + (size_t)r0 * KDIM + g * 64 + (tid & 7) * 8;
        d[0] = *(const f32x4*)s0;
        d[1] = *(const f32x4*)(s0 + 4);
        d[2] = *(const f32x4*)(s0 + (size_t)64 * KDIM);
        d[3] = *(const f32x4*)(s0 + (size_t)64 * KDIM + 4);
        const float* s1 = s0 + (size_t)128 * KDIM;
        d[4] = *(const f32x4*)s1;
        d[5] = *(const f32x4*)(s1 + 4);
        d[6] = *(const f32x4*)(s1 + (size_t)64 * KDIM);
        d[7] = *(const f32x4*)(s1 + (size_t)64 * KDIM + 4);
    };
    auto cvtwriteB = [&](int g, const f32x4* d) {
        bf16x8 h0, h1, h2, h3;
#pragma unroll
        for (int j = 0; j < 4; ++j) {
            h0[j] = (bf16)d[0][j]; h0[4 + j] = (bf16)d[1][j];
            h1[j] = (bf16)d[2][j]; h1[4 + j] = (bf16)d[3][j];
            h2[j] = (bf16)d[4][j]; h2[4 + j] = (bf16)d[5][j];
            h3[j] = (bf16)d[6][j]; h3[4 + j] = (bf16)d[7][j];
        }
        char* dst = smem + (g & 1) * 65536 + 32768 + r0 * 128 + wsw;
        *(bf16x8*)dst = h0;
        *(bf16x8*)(dst + 8192)  = h1;
        *(bf16x8*)(dst + 16384) = h2;
        *(bf16x8*)(dst + 24576) = h3;
    };

    // fragment-read lane constants: chunk c = kk*4+fq, swizzled c^(fr&7)
    const int frq = fr & 7;
    const int cA0 = ((fq    ) ^ frq) << 4;
    const int cA1 = ((4 | fq) ^ frq) << 4;
    const int aoff = wr * 16384 + fr * 128;
    const int boff = 32768 + (wc >> 1) * 16384 + (wc & 1) * 8192 + fr * 128;

    bf16x8 av[4][2];
    bf16x8 bv[4][2];
    f32x4 acc[8][4];
#pragma unroll
    for (int m = 0; m < 8; ++m)
#pragma unroll
        for (int n = 0; n < 4; ++n) acc[m][n] = (f32x4){0.f, 0.f, 0.f, 0.f};

    auto loadA = [&](const char* base, int mh) {
#pragma unroll
        for (int mm = 0; mm < 4; ++mm) {
            const char* p = base + aoff + (mh * 4 + mm) * 2048;
            av[mm][0] = *(const bf16x8*)(p + cA0);
            av[mm][1] = *(const bf16x8*)(p + cA1);
        }
    };
    auto loadB = [&](const char* base, int nh) {
#pragma unroll
        for (int nn = 0; nn < 2; ++nn) {
            const char* p = base + boff + (nh * 2 + nn) * 2048;
            bv[nh * 2 + nn][0] = *(const bf16x8*)(p + cA0);
            bv[nh * 2 + nn][1] = *(const bf16x8*)(p + cA1);
        }
    };
    auto mmaq = [&](int mh, int nh) {
        __builtin_amdgcn_s_setprio(1);
#pragma unroll
        for (int mm = 0; mm < 4; ++mm)
#pragma unroll
            for (int nn = 0; nn < 2; ++nn) {
                const int m = mh * 4 + mm, n = nh * 2 + nn;
                acc[m][n] = __builtin_amdgcn_mfma_f32_16x16x32_bf16(av[mm][0], bv[n][0], acc[m][n], 0, 0, 0);
                acc[m][n] = __builtin_amdgcn_mfma_f32_16x16x32_bf16(av[mm][1], bv[n][1], acc[m][n], 0, 0, 0);
            }
        __builtin_amdgcn_s_setprio(0);
    };

    // ---- prologue: K-tiles 0,1 resident (B via path-specific staging) ----
    if constexpr (BF32) {
        f32x4 p0[8], p1[8];
        loadB32(0, p0); loadB32(1, p1);             // oldest in queue
        stageA(0, 0); stageA(0, 1);
        cvtwriteB(0, p0);                            // auto-wait: vmcnt(12)
        cvtwriteB(1, p1);                            // auto-wait: vmcnt(4)
        VMCNT(0);                                    // A(0) resident
        asm volatile("s_waitcnt lgkmcnt(0)" ::: "memory");
        BARRIER();
    } else {
        stageB16(0, 0); stageB16(0, 1); stageA(0, 0); stageA(0, 1);
        stageB16(1, 0); stageB16(1, 1);
        VMCNT(4);
        BARRIER();
    }

    for (int t = 0; t < NIT; ++t) {
        const bool nl = (t + 1 < NIT);
        const char* d0b = smem;             // K-tile 2t   (dbuf0)
        const char* d1b = smem + 65536;     // K-tile 2t+1 (dbuf1)
        const int ga = 2 * t + 1;
        const int gb = 2 * t + 2;
        const int gc = 2 * t + 3;
        f32x4 blb[8], blc[8];

        // ---- K-tile a (dbuf0) ----
        loadB(d0b, 0); loadA(d0b, 0);       // ph0
        if constexpr (BF32) { if (nl) loadB32(gb, blb); }
        stageA(ga, 0);
        BARRIER(); LGKM0();
        mmaq(0, 0);
        BARRIER();

        loadB(d0b, 1);                      // ph1
        stageA(ga, 1);
        BARRIER(); LGKM0();
        mmaq(0, 1);
        BARRIER();

        loadA(d0b, 1);                      // ph2
        if constexpr (!BF32) { if (nl) stageB16(gb, 0); }
        BARRIER(); LGKM0();
        mmaq(1, 1);
        BARRIER();

        if constexpr (BF32) { if (nl) cvtwriteB(gb, blb); }   // ph3
        else                { if (nl) stageB16(gb, 1); }
        BARRIER(); LGKM0();
        mmaq(1, 0);
        if constexpr (BF32) { VMCNT(0); }
        else                { if (nl) { VMCNT(4); } else { VMCNT(0); } }
        BARRIER();

        // ---- K-tile b (dbuf1) ----
        loadB(d1b, 0); loadA(d1b, 0);       // ph4
        if constexpr (BF32) { if (nl) loadB32(gc, blc); }
        if (nl) stageA(gb, 0);
        BARRIER(); LGKM0();
        mmaq(0, 0);
        BARRIER();

        loadB(d1b, 1);                      // ph5
        if (nl) stageA(gb, 1);
        BARRIER(); LGKM0();
        mmaq(0, 1);
        BARRIER();

        loadA(d1b, 1);                      // ph6
        if constexpr (!BF32) { if (nl) stageB16(gc, 0); }
        BARRIER(); LGKM0();
        mmaq(1, 1);
        BARRIER();

        if constexpr (BF32) { if (nl) cvtwriteB(gc, blc); }   // ph7
        else                { if (nl) stageB16(gc, 1); }
        BARRIER(); LGKM0();
        mmaq(1, 0);
        if (nl) {
            if constexpr (BF32) { VMCNT(0); } else { VMCNT(4); }
            BARRIER();
        }
    }

    // epilogue
    const int gr0 = bm * 256 + wr * 128;
    const int gc0 = bn * 256 + wc * 64;
    if constexpr (RELU_BF16) {
        bf16* Out = (bf16*)OutP;
#pragma unroll
        for (int n = 0; n < 4; ++n) {
            const int col = gc0 + n * 16 + fr;
            const float bb = bias[(size_t)e * NROWS + col];
#pragma unroll
            for (int m = 0; m < 8; ++m)
#pragma unroll
                for (int j = 0; j < 4; ++j) {
                    float v = acc[m][n][j] + bb;
                    v = v > 0.f ? v : 0.f;
                    const int row = gr0 + m * 16 + fq * 4 + j;
                    Out[((size_t)e * MROWS + row) * NROWS + col] = (bf16)v;
                }
        }
    } else {
        float* Out = (float*)OutP;
#pragma unroll
        for (int n = 0; n < 4; ++n) {
            const int col = gc0 + n * 16 + fr;
            const float bb = bias[(size_t)e * NROWS + col];
#pragma unroll
            for (int m = 0; m < 8; ++m)
#pragma unroll
                for (int j = 0; j < 4; ++j) {
                    const int row = gr0 + m * 16 + fq * 4 + j;
                    Out[((size_t)e * MROWS + row) * NROWS + col] = acc[m][n][j] + bb;
                }
        }
    }
}

// ---------------------------------------------------------------------------
extern "C" void kernel_launch(void* const* d_in, const int* in_sizes, int n_in,
                              void* d_out, int out_size, void* d_ws, size_t ws_size,
                              hipStream_t stream)
{
    const float* x  = (const float*)d_in[0];
    const float* w1 = (const float*)d_in[1];
    const float* b1 = (const float*)d_in[2];
    const float* w2 = (const float*)d_in[3];
    const float* b2 = (const float*)d_in[4];
    float* out = (float*)d_out;

    (void)hipFuncSetAttribute(reinterpret_cast<const void*>(&gemm256<M_, true, true>),
                              hipFuncAttributeMaxDynamicSharedMemorySize, 131072);
    (void)hipFuncSetAttribute(reinterpret_cast<const void*>(&gemm256<H_, false, false>),
                              hipFuncAttributeMaxDynamicSharedMemorySize, 131072);

    const size_t xb_sz  = (size_t)E_ * C_ * M_ * sizeof(bf16);   //  32 MB
    const size_t w2t_sz = (size_t)E_ * O_ * H_ * sizeof(bf16);   // 256 MB
    const size_t y1_sz  = (size_t)E_ * C_ * H_ * sizeof(bf16);   // 128 MB

    if (ws_size >= xb_sz + w2t_sz + y1_sz) {
        bf16* xb  = (bf16*)d_ws;
        bf16* w2t = (bf16*)((char*)d_ws + xb_sz);
        bf16* y1  = (bf16*)((char*)d_ws + xb_sz + w2t_sz);

        cvt_f32_bf16<<<2048, 256, 0, stream>>>(x, xb, (size_t)E_ * C_ * M_);
        transpose_w2<<<dim3(O_ / 64, H_ / 64, E_), 256, 0, stream>>>(w2, w2t, 0);

        // gemm1: [E,1024,2048]bf16 x [E,8192,2048]fp32^T -> bf16 y1 (+bias,relu)
        gemm256<M_, true, true><<<dim3(8 * 4 * (H_ / 256)), 512, 131072, stream>>>(
            xb, w1, b1, y1, 4, H_ / 256);
        // gemm2: [E,1024,8192]bf16 x [E,2048,8192]bf16^T -> fp32 out (+bias)
        gemm256<H_, false, false><<<dim3(8 * 4 * (O_ / 256)), 512, 131072, stream>>>(
            y1, w2t, b2, out, 4, O_ / 256);
    } else {
        // per-expert fallback: 4 + 32 + 16 = 52 MB of ws
        bf16* xb  = (bf16*)d_ws;
        bf16* w2t = (bf16*)((char*)d_ws + (size_t)C_ * M_ * sizeof(bf16));
        bf16* y1  = (bf16*)((char*)d_ws + (size_t)C_ * M_ * sizeof(bf16)
                                        + (size_t)O_ * H_ * sizeof(bf16));
        for (int e = 0; e < E_; ++e) {
            cvt_f32_bf16<<<512, 256, 0, stream>>>(x + (size_t)e * C_ * M_, xb, (size_t)C_ * M_);
            transpose_w2<<<dim3(O_ / 64, H_ / 64, 1), 256, 0, stream>>>(w2, w2t, e);
            gemm256<M_, true, true><<<dim3(4 * (H_ / 256)), 512, 131072, stream>>>(
                xb, w1 + (size_t)e * H_ * M_, b1 + (size_t)e * H_, y1, 4, H_ / 256);
            gemm256<H_, false, false><<<dim3(4 * (O_ / 256)), 512, 131072, stream>>>(
                y1, w2t, b2 + (size_t)e * O_, out + (size_t)e * C_ * O_, 4, O_ / 256);
        }
    }
}

// Round 14
// 777.105 us; speedup vs baseline: 1.0478x; 1.0041x over previous
//
#include <hip/hip_runtime.h>
#include <hip/hip_bf16.h>
#include <stddef.h>

// Problem constants
constexpr int E_ = 8;
constexpr int C_ = 1024;
constexpr int M_ = 2048;
constexpr int H_ = 8192;
constexpr int O_ = 2048;

typedef __bf16 bf16;
typedef __bf16 bf16x4 __attribute__((ext_vector_type(4)));
typedef __bf16 bf16x8 __attribute__((ext_vector_type(8)));
typedef float  f32x4  __attribute__((ext_vector_type(4)));

#define GLOAD16(src, dst)                                                        \
    __builtin_amdgcn_global_load_lds(                                            \
        (const __attribute__((address_space(1))) void*)(src),                    \
        (__attribute__((address_space(3))) void*)(dst), 16, 0, 0)

#define BARRIER()  __builtin_amdgcn_s_barrier()
#define LGKM0()    do { asm volatile("s_waitcnt lgkmcnt(0)" ::: "memory");       \
                        __builtin_amdgcn_sched_barrier(0); } while (0)
#define VMCNT(n)   asm volatile("s_waitcnt vmcnt(" #n ")" ::: "memory")

// ---------------------------------------------------------------------------
// fp32 -> bf16 convert (grid-stride, 32B-read/16B-write per lane)
// ---------------------------------------------------------------------------
__global__ __launch_bounds__(256)
void cvt_f32_bf16(const float* __restrict__ in, bf16* __restrict__ out, size_t n)
{
    size_t i = ((size_t)blockIdx.x * blockDim.x + threadIdx.x) * 8;
    const size_t stride = (size_t)gridDim.x * blockDim.x * 8;
    for (; i < n; i += stride) {
        f32x4 v0 = *(const f32x4*)(in + i);
        f32x4 v1 = *(const f32x4*)(in + i + 4);
        bf16x8 o;
#pragma unroll
        for (int j = 0; j < 4; ++j) { o[j] = (bf16)v0[j]; o[j + 4] = (bf16)v1[j]; }
        *(bf16x8*)(out + i) = o;
    }
}

// ---------------------------------------------------------------------------
// Transpose+convert: W2 [E, H, O] fp32 -> W2t [z, O, H] bf16.
// r14 MLP variant: each block handles 4 CONSECUTIVE oo-tiles (4 x 9 KiB LDS
// buffers): 16 independent 16B loads/thread issued before one barrier (4x
// deeper MLP than the 1-tile version) and 4 x 256B adjacent read segments
// per h-row (DRAM page locality). GEMMs untouched.
// ---------------------------------------------------------------------------
__global__ __launch_bounds__(256)
void transpose_w2(const float* __restrict__ W2, bf16* __restrict__ W2t, int e0)
{
    const int e   = e0 + blockIdx.z;
    const int oo0 = blockIdx.x * 4;     // O/64/4 = 8 blocks in x
    const int ho  = blockIdx.y;         // H/64
    const int tid = threadIdx.x;

    __shared__ bf16 t[4][64][72];       // 36864 B; 144B rows, 16B-aligned reads

    const float* base = W2 + (size_t)e * H_ * O_ + (size_t)(ho * 64) * O_;
    const int h_  = tid >> 4;           // 0..15 (x4 via p)
    const int o4  = (tid & 15) * 4;

#pragma unroll
    for (int q4 = 0; q4 < 4; ++q4) {
        const float* src = base + (size_t)(oo0 + q4) * 64;
#pragma unroll
        for (int p = 0; p < 4; ++p) {
            const int h = p * 16 + h_;
            f32x4 v = *(const f32x4*)(src + (size_t)h * O_ + o4);
#pragma unroll
            for (int q = 0; q < 4; ++q) t[q4][o4 + q][h] = (bf16)v[q];
        }
    }
    __syncthreads();

    bf16* dstb = W2t + (size_t)blockIdx.z * O_ * H_ + (size_t)ho * 64;
#pragma unroll
    for (int q4 = 0; q4 < 4; ++q4) {
        bf16* dst = dstb + (size_t)(oo0 + q4) * 64 * H_;
#pragma unroll
        for (int p2 = 0; p2 < 2; ++p2) {
            const int o  = p2 * 32 + (tid >> 3);
            const int h8 = (tid & 7) * 8;
            bf16x8 v = *(const bf16x8*)(&t[q4][o][h8]);
            *(bf16x8*)(dst + (size_t)o * H_ + h8) = v;
        }
    }
}

// ---------------------------------------------------------------------------
// 256x256-tile 8-phase grouped GEMM, BK=64, 2 K-tiles/iter, 512 thr = 8 waves
// (2M x 4N), wave tile 128x64, acc[8][4] f32x4.  CHAMPION — UNCHANGED (r6,
// reproduced 780-783 µs in r11/r13).
// LDS 128 KiB: dbuf (K-tile g -> g&1), each 64 KiB = A0@0 A1@16K B0@32K B1@48K
// (half = 128 rows x 64 k x 2B, rows of 128B). Swizzle: 16B chunk c of row r
// stored at c^(r&7); applied on pre-swizzled gload source / ds_write addr,
// and on the ds_read fragment addr -> conflict-free b128 reads.
//
// BF32=false (gemm2): B staged bf16 via global_load_lds at ph2/3 (gb) and
//   ph6/7 (gc); counted VMCNT(4) at ph3/ph7 (r3-proven schedule).
// BF32=true (gemm1): B read from fp32 global with a 3-PHASE LEAD —
//   8 x f32x4 buffer-loads issued at ph0 (gb) / ph4 (gc); cvt+4 ds_write_b128
//   at ph3 / ph7 (blb/blc iteration-local; in-order vmcnt queue keeps A-stage
//   guarantees). Measured dead ends: r4/r5/r7/r8/r9/r10/r12 (see session log).
// ---------------------------------------------------------------------------
template<int KDIM, bool RELU_BF16, bool BF32>
__global__ __launch_bounds__(512, 2)
void gemm256(const bf16* __restrict__ A, const void* __restrict__ Bv,
             const float* __restrict__ bias, void* __restrict__ OutP,
             int nBM, int nBN)
{
    extern __shared__ char smem[];                  // 131072 B
    constexpr int K2  = KDIM * 2;                   // bf16 row stride bytes
    constexpr int NIT = KDIM / 128;                 // iterations (2 K-tiles each)

    const int tid  = threadIdx.x;
    const int lane = tid & 63;
    const int wid  = tid >> 6;
    const int wr = wid >> 2, wc = wid & 3;
    const int fr = lane & 15, fq = lane >> 4;

    // XCD-aware bijective block swizzle (grid % 8 == 0 by construction)
    const int nwg = gridDim.x;
    const int cpx = nwg >> 3;
    const int b0  = blockIdx.x;
    const int wg  = (b0 & 7) * cpx + (b0 >> 3);
    const int per_e = nBM * nBN;
    const int e  = wg / per_e;
    const int rr = wg - e * per_e;
    const int bn = rr / nBM;
    const int bm = rr - bn * nBM;      // bm fastest: 4 wgs sharing a B panel are
                                       // consecutive -> same XCD after swizzle
    const int MROWS = nBM * 256;
    const int NROWS = nBN * 256;

    const char*  Apan   = (const char*)(A + (size_t)e * MROWS * KDIM + (size_t)bm * 256 * KDIM);
    const char*  Bpan   = (const char*)((const bf16*)Bv + (size_t)e * NROWS * KDIM + (size_t)bn * 256 * KDIM);
    const float* Bpan32 = (const float*)Bv + (size_t)e * NROWS * KDIM + (size_t)bn * 256 * KDIM;

    const int r0  = tid >> 3;                       // 0..63
    const int wsw = ((tid & 7) << 4) ^ ((r0 & 7) << 4);

    auto stageA = [&](int gk, int comp) {           // comp: 0/1 = A row-half
        char* lds = smem + (gk & 1) * 65536 + comp * 16384 + tid * 16;
        const char* src = Apan + (size_t)((comp << 7) + r0) * K2 + (size_t)gk * 128 + wsw;
        GLOAD16(src, lds);
        GLOAD16(src + (size_t)64 * K2, lds + 8192);
    };
    auto stageB16 = [&](int gk, int comp2) {        // bf16 path
        char* lds = smem + (gk & 1) * 65536 + 32768 + comp2 * 16384 + tid * 16;
        const char* src = Bpan + (size_t)((comp2 << 7) + r0) * K2 + (size_t)gk * 128 + wsw;
        GLOAD16(src, lds);
        GLOAD16(src + (size_t)64 * K2, lds + 8192);
    };
    // fp32 path: load BOTH B halves of K-tile g (rows r0, r0+64, 128+r0, 192+r0)
    auto loadB32 = [&](int g, f32x4* d) {
        const float* s0 = Bpan32 + (size_t)r0 * KDIM + g * 64 + (tid & 7) * 8;
        d[0] = *(const f32x4*)s0;
        d[1] = *(const f32x4*)(s0 + 4);
        d[2] = *(const f32x4*)(s0 + (size_t)64 * KDIM);
        d[3] = *(const f32x4*)(s0 + (size_t)64 * KDIM + 4);
        const float* s1 = s0 + (size_t)128 * KDIM;
        d[4] = *(const f32x4*)s1;
        d[5] = *(const f32x4*)(s1 + 4);
        d[6] = *(const f32x4*)(s1 + (size_t)64 * KDIM);
        d[7] = *(const f32x4*)(s1 + (size_t)64 * KDIM + 4);
    };
    auto cvtwriteB = [&](int g, const f32x4* d) {
        bf16x8 h0, h1, h2, h3;
#pragma unroll
        for (int j = 0; j < 4; ++j) {
            h0[j] = (bf16)d[0][j]; h0[4 + j] = (bf16)d[1][j];
            h1[j] = (bf16)d[2][j]; h1[4 + j] = (bf16)d[3][j];
            h2[j] = (bf16)d[4][j]; h2[4 + j] = (bf16)d[5][j];
            h3[j] = (bf16)d[6][j]; h3[4 + j] = (bf16)d[7][j];
        }
        char* dst = smem + (g & 1) * 65536 + 32768 + r0 * 128 + wsw;
        *(bf16x8*)dst = h0;
        *(bf16x8*)(dst + 8192)  = h1;
        *(bf16x8*)(dst + 16384) = h2;
        *(bf16x8*)(dst + 24576) = h3;
    };

    // fragment-read lane constants: chunk c = kk*4+fq, swizzled c^(fr&7)
    const int frq = fr & 7;
    const int cA0 = ((fq    ) ^ frq) << 4;
    const int cA1 = ((4 | fq) ^ frq) << 4;
    const int aoff = wr * 16384 + fr * 128;
    const int boff = 32768 + (wc >> 1) * 16384 + (wc & 1) * 8192 + fr * 128;

    bf16x8 av[4][2];
    bf16x8 bv[4][2];
    f32x4 acc[8][4];
#pragma unroll
    for (int m = 0; m < 8; ++m)
#pragma unroll
        for (int n = 0; n < 4; ++n) acc[m][n] = (f32x4){0.f, 0.f, 0.f, 0.f};

    auto loadA = [&](const char* base, int mh) {
#pragma unroll
        for (int mm = 0; mm < 4; ++mm) {
            const char* p = base + aoff + (mh * 4 + mm) * 2048;
            av[mm][0] = *(const bf16x8*)(p + cA0);
            av[mm][1] = *(const bf16x8*)(p + cA1);
        }
    };
    auto loadB = [&](const char* base, int nh) {
#pragma unroll
        for (int nn = 0; nn < 2; ++nn) {
            const char* p = base + boff + (nh * 2 + nn) * 2048;
            bv[nh * 2 + nn][0] = *(const bf16x8*)(p + cA0);
            bv[nh * 2 + nn][1] = *(const bf16x8*)(p + cA1);
        }
    };
    auto mmaq = [&](int mh, int nh) {
        __builtin_amdgcn_s_setprio(1);
#pragma unroll
        for (int mm = 0; mm < 4; ++mm)
#pragma unroll
            for (int nn = 0; nn < 2; ++nn) {
                const int m = mh * 4 + mm, n = nh * 2 + nn;
                acc[m][n] = __builtin_amdgcn_mfma_f32_16x16x32_bf16(av[mm][0], bv[n][0], acc[m][n], 0, 0, 0);
                acc[m][n] = __builtin_amdgcn_mfma_f32_16x16x32_bf16(av[mm][1], bv[n][1], acc[m][n], 0, 0, 0);
            }
        __builtin_amdgcn_s_setprio(0);
    };

    // ---- prologue: K-tiles 0,1 resident (B via path-specific staging) ----
    if constexpr (BF32) {
        f32x4 p0[8], p1[8];
        loadB32(0, p0); loadB32(1, p1);             // oldest in queue
        stageA(0, 0); stageA(0, 1);
        cvtwriteB(0, p0);                            // auto-wait: vmcnt(12)
        cvtwriteB(1, p1);                            // auto-wait: vmcnt(4)
        VMCNT(0);                                    // A(0) resident
        asm volatile("s_waitcnt lgkmcnt(0)" ::: "memory");
        BARRIER();
    } else {
        stageB16(0, 0); stageB16(0, 1); stageA(0, 0); stageA(0, 1);
        stageB16(1, 0); stageB16(1, 1);
        VMCNT(4);
        BARRIER();
    }

    for (int t = 0; t < NIT; ++t) {
        const bool nl = (t + 1 < NIT);
        const char* d0b = smem;             // K-tile 2t   (dbuf0)
        const char* d1b = smem + 65536;     // K-tile 2t+1 (dbuf1)
        const int ga = 2 * t + 1;
        const int gb = 2 * t + 2;
        const int gc = 2 * t + 3;
        f32x4 blb[8], blc[8];

        // ---- K-tile a (dbuf0) ----
        loadB(d0b, 0); loadA(d0b, 0);       // ph0
        if constexpr (BF32) { if (nl) loadB32(gb, blb); }
        stageA(ga, 0);
        BARRIER(); LGKM0();
        mmaq(0, 0);
        BARRIER();

        loadB(d0b, 1);                      // ph1
        stageA(ga, 1);
        BARRIER(); LGKM0();
        mmaq(0, 1);
        BARRIER();

        loadA(d0b, 1);                      // ph2
        if constexpr (!BF32) { if (nl) stageB16(gb, 0); }
        BARRIER(); LGKM0();
        mmaq(1, 1);
        BARRIER();

        if constexpr (BF32) { if (nl) cvtwriteB(gb, blb); }   // ph3
        else                { if (nl) stageB16(gb, 1); }
        BARRIER(); LGKM0();
        mmaq(1, 0);
        if constexpr (BF32) { VMCNT(0); }
        else                { if (nl) { VMCNT(4); } else { VMCNT(0); } }
        BARRIER();

        // ---- K-tile b (dbuf1) ----
        loadB(d1b, 0); loadA(d1b, 0);       // ph4
        if constexpr (BF32) { if (nl) loadB32(gc, blc); }
        if (nl) stageA(gb, 0);
        BARRIER(); LGKM0();
        mmaq(0, 0);
        BARRIER();

        loadB(d1b, 1);                      // ph5
        if (nl) stageA(gb, 1);
        BARRIER(); LGKM0();
        mmaq(0, 1);
        BARRIER();

        loadA(d1b, 1);                      // ph6
        if constexpr (!BF32) { if (nl) stageB16(gc, 0); }
        BARRIER(); LGKM0();
        mmaq(1, 1);
        BARRIER();

        if constexpr (BF32) { if (nl) cvtwriteB(gc, blc); }   // ph7
        else                { if (nl) stageB16(gc, 1); }
        BARRIER(); LGKM0();
        mmaq(1, 0);
        if (nl) {
            if constexpr (BF32) { VMCNT(0); } else { VMCNT(4); }
            BARRIER();
        }
    }

    // epilogue
    const int gr0 = bm * 256 + wr * 128;
    const int gc0 = bn * 256 + wc * 64;
    if constexpr (RELU_BF16) {
        bf16* Out = (bf16*)OutP;
#pragma unroll
        for (int n = 0; n < 4; ++n) {
            const int col = gc0 + n * 16 + fr;
            const float bb = bias[(size_t)e * NROWS + col];
#pragma unroll
            for (int m = 0; m < 8; ++m)
#pragma unroll
                for (int j = 0; j < 4; ++j) {
                    float v = acc[m][n][j] + bb;
                    v = v > 0.f ? v : 0.f;
                    const int row = gr0 + m * 16 + fq * 4 + j;
                    Out[((size_t)e * MROWS + row) * NROWS + col] = (bf16)v;
                }
        }
    } else {
        float* Out = (float*)OutP;
#pragma unroll
        for (int n = 0; n < 4; ++n) {
            const int col = gc0 + n * 16 + fr;
            const float bb = bias[(size_t)e * NROWS + col];
#pragma unroll
            for (int m = 0; m < 8; ++m)
#pragma unroll
                for (int j = 0; j < 4; ++j) {
                    const int row = gr0 + m * 16 + fq * 4 + j;
                    Out[((size_t)e * MROWS + row) * NROWS + col] = acc[m][n][j] + bb;
                }
        }
    }
}

// ---------------------------------------------------------------------------
extern "C" void kernel_launch(void* const* d_in, const int* in_sizes, int n_in,
                              void* d_out, int out_size, void* d_ws, size_t ws_size,
                              hipStream_t stream)
{
    const float* x  = (const float*)d_in[0];
    const float* w1 = (const float*)d_in[1];
    const float* b1 = (const float*)d_in[2];
    const float* w2 = (const float*)d_in[3];
    const float* b2 = (const float*)d_in[4];
    float* out = (float*)d_out;

    (void)hipFuncSetAttribute(reinterpret_cast<const void*>(&gemm256<M_, true, true>),
                              hipFuncAttributeMaxDynamicSharedMemorySize, 131072);
    (void)hipFuncSetAttribute(reinterpret_cast<const void*>(&gemm256<H_, false, false>),
                              hipFuncAttributeMaxDynamicSharedMemorySize, 131072);

    const size_t xb_sz  = (size_t)E_ * C_ * M_ * sizeof(bf16);   //  32 MB
    const size_t w2t_sz = (size_t)E_ * O_ * H_ * sizeof(bf16);   // 256 MB
    const size_t y1_sz  = (size_t)E_ * C_ * H_ * sizeof(bf16);   // 128 MB

    if (ws_size >= xb_sz + w2t_sz + y1_sz) {
        bf16* xb  = (bf16*)d_ws;
        bf16* w2t = (bf16*)((char*)d_ws + xb_sz);
        bf16* y1  = (bf16*)((char*)d_ws + xb_sz + w2t_sz);

        cvt_f32_bf16<<<2048, 256, 0, stream>>>(x, xb, (size_t)E_ * C_ * M_);
        transpose_w2<<<dim3(O_ / 256, H_ / 64, E_), 256, 0, stream>>>(w2, w2t, 0);

        // gemm1: [E,1024,2048]bf16 x [E,8192,2048]fp32^T -> bf16 y1 (+bias,relu)
        gemm256<M_, true, true><<<dim3(8 * 4 * (H_ / 256)), 512, 131072, stream>>>(
            xb, w1, b1, y1, 4, H_ / 256);
        // gemm2: [E,1024,8192]bf16 x [E,2048,8192]bf16^T -> fp32 out (+bias)
        gemm256<H_, false, false><<<dim3(8 * 4 * (O_ / 256)), 512, 131072, stream>>>(
            y1, w2t, b2, out, 4, O_ / 256);
    } else {
        // per-expert fallback: 4 + 32 + 16 = 52 MB of ws
        bf16* xb  = (bf16*)d_ws;
        bf16* w2t = (bf16*)((char*)d_ws + (size_t)C_ * M_ * sizeof(bf16));
        bf16* y1  = (bf16*)((char*)d_ws + (size_t)C_ * M_ * sizeof(bf16)
                                        + (size_t)O_ * H_ * sizeof(bf16));
        for (int e = 0; e < E_; ++e) {
            cvt_f32_bf16<<<512, 256, 0, stream>>>(x + (size_t)e * C_ * M_, xb, (size_t)C_ * M_);
            transpose_w2<<<dim3(O_ / 256, H_ / 64, 1), 256, 0, stream>>>(w2, w2t, e);
            gemm256<M_, true, true><<<dim3(4 * (H_ / 256)), 512, 131072, stream>>>(
                xb, w1 + (size_t)e * H_ * M_, b1 + (size_t)e * H_, y1, 4, H_ / 256);
            gemm256<H_, false, false><<<dim3(4 * (O_ / 256)), 512, 131072, stream>>>(
                y1, w2t, b2 + (size_t)e * O_, out + (size_t)e * C_ * O_, 4, O_ / 256);
        }
    }
}